// Round 1
// baseline (2228.748 us; speedup 1.0000x reference)
//
#include <hip/hip_runtime.h>
#include <math.h>

#define NEURONS 256
#define TS 16          // samples per block
#define NTHREADS 256   // 16 samples x 16 neuron-groups

__device__ __forceinline__ float softplus_f(float z) {
    return z > 15.f ? z : log1pf(expf(z));
}

extern "C" __global__ __launch_bounds__(NTHREADS, 2)
void lode_fused(const float* __restrict__ x,
                const float* __restrict__ W0, const float* __restrict__ b0,
                const float* __restrict__ W1, const float* __restrict__ b1,
                const float* __restrict__ Wd, const float* __restrict__ bd,
                const float* __restrict__ Wo, const float* __restrict__ bo,
                const float* __restrict__ Wv,
                float* __restrict__ out, int n)
{
    // k-major activation tiles: A[k][s], conflict-free broadcast reads in phase 2
    __shared__ float A_h [NEURONS * TS];
    __shared__ float A_ta[NEURONS * TS];
    __shared__ float A_tb[NEURONS * TS];

    const int tid = threadIdx.x;
    const int s   = tid >> 4;   // sample-in-tile 0..15
    const int jg  = tid & 15;   // neuron group 0..15 (16 neurons each)

    int sg = blockIdx.x * TS + s;
    const bool valid = (sg < n);
    if (!valid) sg = n - 1;

    const float q0   = x[sg * 6 + 0];
    const float q1   = x[sg * 6 + 1];
    const float u    = x[sg * 6 + 2];
    const float vv   = x[sg * 6 + 3];
    const float tau0 = x[sg * 6 + 4];
    const float tau1 = x[sg * 6 + 5];

    float sn0, cs0, sn1, cs1;
    sincosf(q0, &sn0, &cs0);
    sincosf(q1, &sn1, &cs1);

    // ---------- phase 1: layer 1 + tangent activations into LDS ----------
    // emb = [cos q0, cos q1, sin q0, sin q1]
    // t0_k = (1-h^2) * ( -sin(qk)*W0[k,:] + cos(qk)*W0[2+k,:] )
    #pragma unroll
    for (int jj = 0; jj < 16; ++jj) {
        const int j = jg * 16 + jj;
        const float w00 = W0[0 * NEURONS + j];
        const float w01 = W0[1 * NEURONS + j];
        const float w02 = W0[2 * NEURONS + j];
        const float w03 = W0[3 * NEURONS + j];
        float z = b0[j];
        z = fmaf(cs0, w00, z);
        z = fmaf(cs1, w01, z);
        z = fmaf(sn0, w02, z);
        z = fmaf(sn1, w03, z);
        const float h  = tanhf(z);
        const float dt = 1.f - h * h;
        const float ua = fmaf(-sn0, w00, cs0 * w02);
        const float ub = fmaf(-sn1, w01, cs1 * w03);
        A_h [j * TS + s] = h;
        A_ta[j * TS + s] = dt * ua;
        A_tb[j * TS + s] = dt * ub;
    }
    __syncthreads();

    // ---------- phase 2: triple matvec vs shared W1 (register-tiled) ----------
    float acc_h[16], acc_ta[16], acc_tb[16];
    #pragma unroll
    for (int i = 0; i < 16; ++i) {
        acc_h [i] = b1[jg * 16 + i];
        acc_ta[i] = 0.f;
        acc_tb[i] = 0.f;
    }

    const float4* __restrict__ W1v = reinterpret_cast<const float4*>(W1) + jg * 4;
    #pragma unroll 2
    for (int k = 0; k < NEURONS; ++k) {
        const float ah = A_h [k * TS + s];
        const float ta = A_ta[k * TS + s];
        const float tb = A_tb[k * TS + s];
        #pragma unroll
        for (int ii = 0; ii < 4; ++ii) {
            const float4 w = W1v[k * 64 + ii];
            acc_h [ii*4+0] = fmaf(ah, w.x, acc_h [ii*4+0]);
            acc_h [ii*4+1] = fmaf(ah, w.y, acc_h [ii*4+1]);
            acc_h [ii*4+2] = fmaf(ah, w.z, acc_h [ii*4+2]);
            acc_h [ii*4+3] = fmaf(ah, w.w, acc_h [ii*4+3]);
            acc_ta[ii*4+0] = fmaf(ta, w.x, acc_ta[ii*4+0]);
            acc_ta[ii*4+1] = fmaf(ta, w.y, acc_ta[ii*4+1]);
            acc_ta[ii*4+2] = fmaf(ta, w.z, acc_ta[ii*4+2]);
            acc_ta[ii*4+3] = fmaf(ta, w.w, acc_ta[ii*4+3]);
            acc_tb[ii*4+0] = fmaf(tb, w.x, acc_tb[ii*4+0]);
            acc_tb[ii*4+1] = fmaf(tb, w.y, acc_tb[ii*4+1]);
            acc_tb[ii*4+2] = fmaf(tb, w.z, acc_tb[ii*4+2]);
            acc_tb[ii*4+3] = fmaf(tb, w.w, acc_tb[ii*4+3]);
        }
    }

    // ---------- heads: partial dot products over this thread's 16 neurons ----------
    float ph_d0 = 0.f, ph_d1 = 0.f, ph_o = 0.f;
    float pa_d0 = 0.f, pa_d1 = 0.f, pa_o = 0.f, pa_v = 0.f;
    float pb_d0 = 0.f, pb_d1 = 0.f, pb_o = 0.f, pb_v = 0.f;
    #pragma unroll
    for (int i = 0; i < 16; ++i) {
        const int j = jg * 16 + i;
        const float h1  = tanhf(acc_h[i]);
        const float dt  = 1.f - h1 * h1;
        const float t1a = dt * acc_ta[i];
        const float t1b = dt * acc_tb[i];
        const float wd0 = Wd[2 * j + 0];
        const float wd1 = Wd[2 * j + 1];
        const float wo  = Wo[j];
        const float wvj = Wv[j];
        ph_d0 = fmaf(h1,  wd0, ph_d0);
        ph_d1 = fmaf(h1,  wd1, ph_d1);
        ph_o  = fmaf(h1,  wo,  ph_o);
        pa_d0 = fmaf(t1a, wd0, pa_d0);
        pa_d1 = fmaf(t1a, wd1, pa_d1);
        pa_o  = fmaf(t1a, wo,  pa_o);
        pa_v  = fmaf(t1a, wvj, pa_v);
        pb_d0 = fmaf(t1b, wd0, pb_d0);
        pb_d1 = fmaf(t1b, wd1, pb_d1);
        pb_o  = fmaf(t1b, wo,  pb_o);
        pb_v  = fmaf(t1b, wvj, pb_v);
    }

    // reduce across the 16 threads of this sample (lane bits 0..3 = jg)
    #pragma unroll
    for (int m = 1; m < 16; m <<= 1) {
        ph_d0 += __shfl_xor(ph_d0, m);
        ph_d1 += __shfl_xor(ph_d1, m);
        ph_o  += __shfl_xor(ph_o,  m);
        pa_d0 += __shfl_xor(pa_d0, m);
        pa_d1 += __shfl_xor(pa_d1, m);
        pa_o  += __shfl_xor(pa_o,  m);
        pa_v  += __shfl_xor(pa_v,  m);
        pb_d0 += __shfl_xor(pb_d0, m);
        pb_d1 += __shfl_xor(pb_d1, m);
        pb_o  += __shfl_xor(pb_o,  m);
        pb_v  += __shfl_xor(pb_v,  m);
    }

    // ---------- per-sample dynamics epilogue ----------
    if (valid && jg == 0) {
        const float zd0 = ph_d0 + bd[0];
        const float zd1 = ph_d1 + bd[1];
        const float zo  = ph_o  + bo[0];

        const float ld0 = softplus_f(zd0) + 1e-4f;
        const float ld1 = softplus_f(zd1) + 1e-4f;
        const float lo  = zo;

        const float sg0 = 1.f / (1.f + expf(-zd0));
        const float sg1 = 1.f / (1.f + expf(-zd1));

        // d l / d q_k
        const float ld0a = sg0 * pa_d0, ld0b = sg0 * pb_d0;
        const float ld1a = sg1 * pa_d1, ld1b = sg1 * pb_d1;
        const float loa  = pa_o,        lob  = pb_o;
        const float ga   = pa_v,        gb   = pb_v;   // dV/dq

        // H = L L^T + eps I
        const float H00 = fmaf(ld0, ld0, 1e-4f);
        const float H01 = ld0 * lo;
        const float H11 = fmaf(lo, lo, fmaf(ld1, ld1, 1e-4f));

        // dH/dq_k
        const float dH00a = 2.f * ld0 * ld0a, dH00b = 2.f * ld0 * ld0b;
        const float dH01a = fmaf(ld0a, lo, ld0 * loa);
        const float dH01b = fmaf(ld0b, lo, ld0 * lob);
        const float dH11a = 2.f * fmaf(lo, loa, ld1 * ld1a);
        const float dH11b = 2.f * fmaf(lo, lob, ld1 * ld1b);

        // (dH/dq_k) @ qd
        const float wa0 = fmaf(dH00a, u, dH01a * vv);
        const float wa1 = fmaf(dH01a, u, dH11a * vv);
        const float wb0 = fmaf(dH00b, u, dH01b * vv);
        const float wb1 = fmaf(dH01b, u, dH11b * vv);

        // qd^T dH/dq_k qd
        const float QFa = dH00a*u*u + 2.f*dH01a*u*vv + dH11a*vv*vv;
        const float QFb = dH00b*u*u + 2.f*dH01b*u*vv + dH11b*vv*vv;

        const float C0 = fmaf(wa0, u, wb0 * vv) - 0.5f * QFa;
        const float C1 = fmaf(wa1, u, wb1 * vv) - 0.5f * QFb;

        const float r0 = tau0 - C0 - ga;
        const float r1 = tau1 - C1 - gb;

        const float det = fmaf(H00, H11, -H01 * H01);
        const float inv = 1.f / det;
        const float qdd0 = (H11 * r0 - H01 * r1) * inv;
        const float qdd1 = (H00 * r1 - H01 * r0) * inv;

        out[sg * 6 + 0] = u;
        out[sg * 6 + 1] = vv;
        out[sg * 6 + 2] = qdd0;
        out[sg * 6 + 3] = qdd1;
        out[sg * 6 + 4] = 0.f;
        out[sg * 6 + 5] = 0.f;
    }
}

extern "C" void kernel_launch(void* const* d_in, const int* in_sizes, int n_in,
                              void* d_out, int out_size, void* d_ws, size_t ws_size,
                              hipStream_t stream) {
    // dict order: t, x, W0, b0, W1, b1, Wd, bd, Wo, bo, Wv, bv
    const float* x  = (const float*)d_in[1];
    const float* W0 = (const float*)d_in[2];
    const float* b0 = (const float*)d_in[3];
    const float* W1 = (const float*)d_in[4];
    const float* b1 = (const float*)d_in[5];
    const float* Wd = (const float*)d_in[6];
    const float* bd = (const float*)d_in[7];
    const float* Wo = (const float*)d_in[8];
    const float* bo = (const float*)d_in[9];
    const float* Wv = (const float*)d_in[10];
    float* out = (float*)d_out;

    const int n = in_sizes[1] / 6;
    const int grid = (n + TS - 1) / TS;
    lode_fused<<<grid, NTHREADS, 0, stream>>>(x, W0, b0, W1, b1, Wd, bd, Wo, bo, Wv,
                                              out, n);
}

// Round 2
// 376.287 us; speedup vs baseline: 5.9230x; 5.9230x over previous
//
#include <hip/hip_runtime.h>
#include <math.h>

#define SB 32          // samples per block
#define NTHREADS 256   // 4 waves

typedef short short8 __attribute__((ext_vector_type(8)));
typedef float f32x4  __attribute__((ext_vector_type(4)));

__device__ __forceinline__ unsigned short f2bf(float f) {
    unsigned int u = __builtin_bit_cast(unsigned int, f);
    unsigned int r = (u + 0x7FFFu + ((u >> 16) & 1u)) >> 16;   // RNE
    return (unsigned short)r;
}
__device__ __forceinline__ float bf2f(unsigned short h) {
    unsigned int u = ((unsigned int)h) << 16;
    return __builtin_bit_cast(float, u);
}
__device__ __forceinline__ float softplus_f(float z) {
    return z > 15.f ? z : log1pf(expf(z));
}

// ---- prep: split W1 into bf16 hi/lo, swizzled into MFMA B-fragment order ----
// frag slot idx = (nt*8+ks)*64 + lane ; element i: B[k][n], k=ks*32+(lane>>4)*8+i,
// n = nt*16 + (lane&15)
__global__ void prep_w1(const float* __restrict__ W1,
                        unsigned short* __restrict__ whi,
                        unsigned short* __restrict__ wlo)
{
    int idx = blockIdx.x * blockDim.x + threadIdx.x;
    if (idx >= 16 * 8 * 64) return;
    const int l  = idx & 63;
    const int ks = (idx >> 6) & 7;
    const int nt = idx >> 9;
    const int k0 = ks * 32 + (l >> 4) * 8;
    const int n  = nt * 16 + (l & 15);
    #pragma unroll
    for (int i = 0; i < 8; ++i) {
        const float f = W1[(k0 + i) * 256 + n];
        const unsigned short hi = f2bf(f);
        const unsigned short lo = f2bf(f - bf2f(hi));
        whi[idx * 8 + i] = hi;
        wlo[idx * 8 + i] = lo;
    }
}

// LDS A-tile fragment layout: slot(t, ks, lane) = t*520 + ks*65 + lane  (uint4 slots)
// Mtile 2w   : rows 0-7 = h_hi (samples 8w..8w+7), rows 8-15 = h_lo
// Mtile 2w+1 : rows 0-7 = ta,                       rows 8-15 = tb
__global__ __launch_bounds__(NTHREADS, 2)
void lode_mfma(const float* __restrict__ x,
               const float* __restrict__ W0, const float* __restrict__ b0,
               const unsigned short* __restrict__ whi,
               const unsigned short* __restrict__ wlo,
               const float* __restrict__ b1,
               const float* __restrict__ Wd, const float* __restrict__ bd,
               const float* __restrict__ Wo, const float* __restrict__ bo,
               const float* __restrict__ Wv,
               float* __restrict__ out, int n)
{
    __shared__ uint4 A_lds[4160];   // 8 Mtiles * (8 ksteps * 65-slot padded stride)

    const int tid = threadIdx.x;

    // ---------------- phase 1: layer-1 activations -> LDS fragments ----------------
    {
        const int sb = tid >> 3;          // sample in block 0..31
        const int c  = tid & 7;           // kstep (32 neurons)
        const int wv_ = sb >> 3;          // owning wave
        const int sl  = sb & 7;           // sample in wave
        int sg = blockIdx.x * SB + sb;
        if (sg >= n) sg = n - 1;

        const float q0 = x[sg * 6 + 0];
        const float q1 = x[sg * 6 + 1];
        float sn0, cs0, sn1, cs1;
        sincosf(q0, &sn0, &cs0);
        sincosf(q1, &sn1, &cs1);

        const int t0 = 2 * wv_;
        const int t1t = 2 * wv_ + 1;

        #pragma unroll
        for (int g = 0; g < 4; ++g) {
            short8 hi8, lo8, ta8, tb8;
            #pragma unroll
            for (int i = 0; i < 8; ++i) {
                const int j = c * 32 + g * 8 + i;
                const float w00 = W0[0 * 256 + j];
                const float w01 = W0[1 * 256 + j];
                const float w02 = W0[2 * 256 + j];
                const float w03 = W0[3 * 256 + j];
                float z = b0[j];
                z = fmaf(cs0, w00, z);
                z = fmaf(cs1, w01, z);
                z = fmaf(sn0, w02, z);
                z = fmaf(sn1, w03, z);
                const float h  = tanhf(z);
                const float dt = 1.f - h * h;
                const float ua = fmaf(-sn0, w00, cs0 * w02);
                const float ub = fmaf(-sn1, w01, cs1 * w03);
                const unsigned short hh = f2bf(h);
                const unsigned short hl = f2bf(h - bf2f(hh));
                hi8[i] = (short)hh;
                lo8[i] = (short)hl;
                ta8[i] = (short)f2bf(dt * ua);
                tb8[i] = (short)f2bf(dt * ub);
            }
            const int lhi = sl + g * 16;
            const int llo = 8 + sl + g * 16;
            *reinterpret_cast<short8*>(&A_lds[t0  * 520 + c * 65 + lhi]) = hi8;
            *reinterpret_cast<short8*>(&A_lds[t0  * 520 + c * 65 + llo]) = lo8;
            *reinterpret_cast<short8*>(&A_lds[t1t * 520 + c * 65 + lhi]) = ta8;
            *reinterpret_cast<short8*>(&A_lds[t1t * 520 + c * 65 + llo]) = tb8;
        }
    }
    __syncthreads();

    // ---------------- phase 2: MFMA GEMM + fused per-ntile epilogue ----------------
    const int wave = tid >> 6;
    const int lane = tid & 63;

    short8 aF0[8], aF1[8];
    #pragma unroll
    for (int ks = 0; ks < 8; ++ks) {
        aF0[ks] = *reinterpret_cast<const short8*>(&A_lds[(2 * wave)     * 520 + ks * 65 + lane]);
        aF1[ks] = *reinterpret_cast<const short8*>(&A_lds[(2 * wave + 1) * 520 + ks * 65 + lane]);
    }

    const short8* __restrict__ Whi8 = reinterpret_cast<const short8*>(whi);
    const short8* __restrict__ Wlo8 = reinterpret_cast<const short8*>(wlo);

    float ph0[4] = {0,0,0,0}, ph1[4] = {0,0,0,0}, pho[4] = {0,0,0,0};
    float pt0[4] = {0,0,0,0}, pt1[4] = {0,0,0,0}, pto[4] = {0,0,0,0}, ptv[4] = {0,0,0,0};

    const int col = lane & 15;

    #pragma unroll 1
    for (int nt = 0; nt < 16; ++nt) {
        const int fbase = nt * 8 * 64 + lane;
        // issue small epilogue loads early
        const int ncol = nt * 16 + col;
        const float2 wd = *reinterpret_cast<const float2*>(&Wd[2 * ncol]);
        const float wo  = Wo[ncol];
        const float wvv = Wv[ncol];
        const float b1v = b1[ncol];

        short8 bh[8], bl[8];
        #pragma unroll
        for (int ks = 0; ks < 8; ++ks) {
            bh[ks] = Whi8[fbase + ks * 64];
            bl[ks] = Wlo8[fbase + ks * 64];
        }

        f32x4 c1a = {0.f, 0.f, 0.f, 0.f};   // {h_hi, h_lo} rows x W_hi
        f32x4 c1b = {0.f, 0.f, 0.f, 0.f};   // {ta, tb} rows x W_hi
        f32x4 c2  = {0.f, 0.f, 0.f, 0.f};   // {h_hi, h_lo} rows x W_lo
        #pragma unroll
        for (int ks = 0; ks < 8; ++ks) {
            c1a = __builtin_amdgcn_mfma_f32_16x16x32_bf16(aF0[ks], bh[ks], c1a, 0, 0, 0);
            c1b = __builtin_amdgcn_mfma_f32_16x16x32_bf16(aF1[ks], bh[ks], c1b, 0, 0, 0);
            c2  = __builtin_amdgcn_mfma_f32_16x16x32_bf16(aF0[ks], bl[ks], c2,  0, 0, 0);
        }

        // epilogue: z = hi-part + partner(lo-part) + b1 ; tanh ; head partials
        #pragma unroll
        for (int r = 0; r < 4; ++r) {
            const float zs = c1a[r] + c2[r];
            const float zp = __shfl_xor(zs, 32);
            const float z  = zs + zp + b1v;
            const float h1 = tanhf(z);
            const float dt = 1.f - h1 * h1;
            const float t1 = dt * c1b[r];   // ta in lanes<32, tb in lanes>=32
            ph0[r] = fmaf(h1, wd.x, ph0[r]);
            ph1[r] = fmaf(h1, wd.y, ph1[r]);
            pho[r] = fmaf(h1, wo,  pho[r]);
            pt0[r] = fmaf(t1, wd.x, pt0[r]);
            pt1[r] = fmaf(t1, wd.y, pt1[r]);
            pto[r] = fmaf(t1, wo,  pto[r]);
            ptv[r] = fmaf(t1, wvv, ptv[r]);
        }
    }

    // column reduction across the 16 lanes holding this row
    #pragma unroll
    for (int r = 0; r < 4; ++r) {
        #pragma unroll
        for (int m = 1; m < 16; m <<= 1) {
            ph0[r] += __shfl_xor(ph0[r], m);
            ph1[r] += __shfl_xor(ph1[r], m);
            pho[r] += __shfl_xor(pho[r], m);
            pt0[r] += __shfl_xor(pt0[r], m);
            pt1[r] += __shfl_xor(pt1[r], m);
            pto[r] += __shfl_xor(pto[r], m);
            ptv[r] += __shfl_xor(ptv[r], m);
        }
    }
    // fetch opposite-half tangent sums (lanes<32 get tb)
    float qt0[4], qt1[4], qto[4], qtv[4];
    #pragma unroll
    for (int r = 0; r < 4; ++r) {
        qt0[r] = __shfl_xor(pt0[r], 32);
        qt1[r] = __shfl_xor(pt1[r], 32);
        qto[r] = __shfl_xor(pto[r], 32);
        qtv[r] = __shfl_xor(ptv[r], 32);
    }

    if (lane < 32 && (lane & 15) == 0) {
        const float bd0 = bd[0], bd1 = bd[1], bo0 = bo[0];
        #pragma unroll
        for (int r = 0; r < 4; ++r) {
            const int s  = ((lane >> 4) << 2) + r;
            const int sg = blockIdx.x * SB + wave * 8 + s;
            if (sg < n) {
                const float u    = x[sg * 6 + 2];
                const float vv   = x[sg * 6 + 3];
                const float tau0 = x[sg * 6 + 4];
                const float tau1 = x[sg * 6 + 5];

                const float zd0 = ph0[r] + bd0;
                const float zd1 = ph1[r] + bd1;
                const float zo  = pho[r] + bo0;

                const float ld0 = softplus_f(zd0) + 1e-4f;
                const float ld1 = softplus_f(zd1) + 1e-4f;
                const float lo  = zo;

                const float sg0 = 1.f / (1.f + expf(-zd0));
                const float sg1 = 1.f / (1.f + expf(-zd1));

                const float pa_d0 = pt0[r], pa_d1 = pt1[r], pa_o = pto[r], pa_v = ptv[r];
                const float pb_d0 = qt0[r], pb_d1 = qt1[r], pb_o = qto[r], pb_v = qtv[r];

                const float ld0a = sg0 * pa_d0, ld0b = sg0 * pb_d0;
                const float ld1a = sg1 * pa_d1, ld1b = sg1 * pb_d1;
                const float loa  = pa_o,        lob  = pb_o;
                const float ga   = pa_v,        gb   = pb_v;

                const float H00 = fmaf(ld0, ld0, 1e-4f);
                const float H01 = ld0 * lo;
                const float H11 = fmaf(lo, lo, fmaf(ld1, ld1, 1e-4f));

                const float dH00a = 2.f * ld0 * ld0a, dH00b = 2.f * ld0 * ld0b;
                const float dH01a = fmaf(ld0a, lo, ld0 * loa);
                const float dH01b = fmaf(ld0b, lo, ld0 * lob);
                const float dH11a = 2.f * fmaf(lo, loa, ld1 * ld1a);
                const float dH11b = 2.f * fmaf(lo, lob, ld1 * ld1b);

                const float wa0 = fmaf(dH00a, u, dH01a * vv);
                const float wa1 = fmaf(dH01a, u, dH11a * vv);
                const float wb0 = fmaf(dH00b, u, dH01b * vv);
                const float wb1 = fmaf(dH01b, u, dH11b * vv);

                const float QFa = dH00a*u*u + 2.f*dH01a*u*vv + dH11a*vv*vv;
                const float QFb = dH00b*u*u + 2.f*dH01b*u*vv + dH11b*vv*vv;

                const float C0 = fmaf(wa0, u, wb0 * vv) - 0.5f * QFa;
                const float C1 = fmaf(wa1, u, wb1 * vv) - 0.5f * QFb;

                const float r0 = tau0 - C0 - ga;
                const float r1 = tau1 - C1 - gb;

                const float det = fmaf(H00, H11, -H01 * H01);
                const float inv = 1.f / det;
                const float qdd0 = (H11 * r0 - H01 * r1) * inv;
                const float qdd1 = (H00 * r1 - H01 * r0) * inv;

                out[sg * 6 + 0] = u;
                out[sg * 6 + 1] = vv;
                out[sg * 6 + 2] = qdd0;
                out[sg * 6 + 3] = qdd1;
                out[sg * 6 + 4] = 0.f;
                out[sg * 6 + 5] = 0.f;
            }
        }
    }
}

extern "C" void kernel_launch(void* const* d_in, const int* in_sizes, int n_in,
                              void* d_out, int out_size, void* d_ws, size_t ws_size,
                              hipStream_t stream) {
    // dict order: t, x, W0, b0, W1, b1, Wd, bd, Wo, bo, Wv, bv
    const float* x  = (const float*)d_in[1];
    const float* W0 = (const float*)d_in[2];
    const float* b0 = (const float*)d_in[3];
    const float* W1 = (const float*)d_in[4];
    const float* b1 = (const float*)d_in[5];
    const float* Wd = (const float*)d_in[6];
    const float* bd = (const float*)d_in[7];
    const float* Wo = (const float*)d_in[8];
    const float* bo = (const float*)d_in[9];
    const float* Wv = (const float*)d_in[10];
    float* out = (float*)d_out;

    unsigned short* whi = (unsigned short*)d_ws;            // 65536 bf16 = 128KB
    unsigned short* wlo = whi + 65536;                      // 65536 bf16 = 128KB

    const int n = in_sizes[1] / 6;

    prep_w1<<<32, 256, 0, stream>>>(W1, whi, wlo);

    const int grid = (n + SB - 1) / SB;
    lode_mfma<<<grid, NTHREADS, 0, stream>>>(x, W0, b0, whi, wlo, b1,
                                             Wd, bd, Wo, bo, Wv, out, n);
}